// Round 4
// baseline (2388.018 us; speedup 1.0000x reference)
//
#include <hip/hip_runtime.h>
#include <hip/hip_bf16.h>
#include <stdint.h>

// GroupLinear: out[l,o] = sum_{g,i,j} x1[l,g*64+i]*x2[l,g*64+j]*W[o,(g*64+i)*64+j] + b[o]
// == GEMM C = Z * W^T, Z[l,k]=x1*x2 built on the fly (K-slab of 64 = fixed (g,i), j contiguous).
// Round 4: B staged via REGULAR vector loads + ds_write (global_load_lds traffic is not
// retained in L2 on gfx950 -> r2/r3 re-fetched W 17x from LLC, 2.4 GB). Register
// double-buffer (unroll-by-2) keeps next iter's B loads in flight through the MFMA phase.
// Padded LDS stride 72 for both tiles; 36 KB LDS -> 4 blocks/CU, grid 1024 = exact residency.

#define L_DIM 2048
#define H_DIM 1024
#define O_DIM 1024
#define BSZ   64
#define KDIM  65536

constexpr int BM = 128, BN = 128, BK = 64;
constexpr int SPLITK = 8;
constexpr int NTILE = O_DIM / BN;             // 8 N-tiles
constexpr int MTILE = L_DIM / BM;             // 16 M-tiles
constexpr int KITERS = (KDIM / BK) / SPLITK;  // 128 K-iters per block
constexpr int STR = 72;   // LDS row stride in shorts (64 + 8 pad; 144B rows -> 2-way conflicts = free)

typedef __attribute__((ext_vector_type(8))) short bf16x8;
typedef __attribute__((ext_vector_type(8))) unsigned short u16x8;
typedef __attribute__((ext_vector_type(4))) float f32x4;

__device__ __forceinline__ unsigned short f2b(float x) {
    __hip_bfloat16 h = __float2bfloat16(x);
    return __builtin_bit_cast(unsigned short, h);
}

// ---- W fp32 -> bf16, coalesced grid-strided passes ----
__global__ __launch_bounds__(256) void w_convert(const float* __restrict__ W,
                                                 unsigned short* __restrict__ Wb) {
    const size_t idx = (size_t)blockIdx.x * 256 + threadIdx.x;    // f32x4 chunk id
    const size_t stride = (size_t)gridDim.x * 256;
    const f32x4* src = reinterpret_cast<const f32x4*>(W);
    ushort4* dst = reinterpret_cast<ushort4*>(Wb);
    #pragma unroll
    for (int p = 0; p < 4; ++p) {
        f32x4 v = src[idx + (size_t)p * stride];
        ushort4 h;
        h.x = f2b(v.x); h.y = f2b(v.y); h.z = f2b(v.z); h.w = f2b(v.w);
        dst[idx + (size_t)p * stride] = h;
    }
}

// ---- out[l][o] = bias[o] (atomic-accumulation base) ----
__global__ __launch_bounds__(256) void gl_init(const float* __restrict__ bias,
                                               float* __restrict__ out) {
    int idx = blockIdx.x * 256 + threadIdx.x;          // float4 index
    int o = (idx * 4) & (O_DIM - 1);
    f32x4 bv = *reinterpret_cast<const f32x4*>(bias + o);
    reinterpret_cast<f32x4*>(out)[idx] = bv;
}

// ---- main GEMM ----
__global__ __launch_bounds__(256, 4) void gl_gemm(const float* __restrict__ x1,
                                                  const float* __restrict__ x2,
                                                  const unsigned short* __restrict__ Wb,
                                                  float* __restrict__ out) {
    __shared__ unsigned short Ab[BM * STR];    // 18 KB
    __shared__ unsigned short Bb[BN * STR];    // 18 KB

    const int tid  = threadIdx.x;
    const int lane = tid & 63;
    const int wid  = tid >> 6;
    const int wm   = (wid >> 1) * 64;   // wave row offset in tile
    const int wn   = (wid & 1) * 64;    // wave col offset in tile
    const int quad = lane >> 4;
    const int l16  = lane & 15;

    // n in low 3 bits: all 16 m-blocks + 8 k-groups of one n-slab co-locate per XCD
    const int id   = blockIdx.x;
    const int n0   = (id & 7) * BN;
    const int m0   = ((id >> 3) & 15) * BM;
    const int kk0  = (id >> 7) * KITERS;

    const int srow = tid >> 4;          // A staging row base (+16 per c)
    const int scol = (tid & 15) * 4;    // A staging float col (0..60)

    // B staging: pass p covers rows p*32 + (tid>>3), chunk (tid&7)*8 shorts (16B).
    const int brow   = tid >> 3;        // 0..31
    const int bchunk = (tid & 7) * 8;   // short offset 0..56
    const unsigned short* gB =
        Wb + (size_t)(n0 + brow) * KDIM + (size_t)kk0 * BK + bchunk;
    const int blds = brow * STR + bchunk;

    f32x4 acc[4][4] = {};
    u16x8 bufA[4], bufB[4];

    // preload iter 0
    #pragma unroll
    for (int p = 0; p < 4; ++p)
        bufA[p] = *reinterpret_cast<const u16x8*>(gB + (size_t)p * 32 * KDIM);

    auto step = [&](int it, u16x8* curb, u16x8* nxtb, bool pf) {
        const int kk = kk0 + it;
        const int g = kk >> 6;          // 64 iters per g
        const int i = kk & 63;

        __syncthreads();                // previous iter's fragment reads done

        // B tile: regs -> LDS (vmcnt wait on curb's loads, issued one iter ago)
        #pragma unroll
        for (int p = 0; p < 4; ++p)
            *reinterpret_cast<u16x8*>(&Bb[blds + p * 32 * STR]) = curb[p];

        // prefetch next iter's B into the other buffer; in flight through compute
        if (pf) {
            const unsigned short* gp = gB + (size_t)(it + 1) * BK;
            #pragma unroll
            for (int p = 0; p < 4; ++p)
                nxtb[p] = *reinterpret_cast<const u16x8*>(gp + (size_t)p * 32 * KDIM);
        }

        // A tile: z[r][j] = x1[m0+r][g*64+i] * x2[m0+r][g*64+j] (x1/x2 are L1/L2-hot)
        #pragma unroll
        for (int c = 0; c < 8; ++c) {
            const int r = srow + c * 16;
            const float x1v = x1[(m0 + r) * H_DIM + g * BSZ + i];
            const f32x4 v = *reinterpret_cast<const f32x4*>(
                &x2[(m0 + r) * H_DIM + g * BSZ + scol]);
            ushort4 h;
            h.x = f2b(v.x * x1v); h.y = f2b(v.y * x1v);
            h.z = f2b(v.z * x1v); h.w = f2b(v.w * x1v);
            *reinterpret_cast<ushort4*>(&Ab[r * STR + scol]) = h;
        }
        __syncthreads();                // staging visible

        #pragma unroll
        for (int ks = 0; ks < 2; ++ks) {
            const int koff = ks * 32 + quad * 8;   // A[m][k=quad*8+j] layout
            bf16x8 af[4], bfr[4];
            #pragma unroll
            for (int mt = 0; mt < 4; ++mt)
                af[mt] = *reinterpret_cast<const bf16x8*>(
                    &Ab[(wm + mt * 16 + l16) * STR + koff]);
            #pragma unroll
            for (int nt = 0; nt < 4; ++nt)
                bfr[nt] = *reinterpret_cast<const bf16x8*>(
                    &Bb[(wn + nt * 16 + l16) * STR + koff]);
            #pragma unroll
            for (int mt = 0; mt < 4; ++mt)
                #pragma unroll
                for (int nt = 0; nt < 4; ++nt)
                    acc[mt][nt] = __builtin_amdgcn_mfma_f32_16x16x32_bf16(
                        af[mt], bfr[nt], acc[mt][nt], 0, 0, 0);
        }
    };

    for (int it = 0; it < KITERS; it += 2) {
        step(it,     bufA, bufB, true);
        step(it + 1, bufB, bufA, it + 2 < KITERS);
    }

    // Epilogue: accumulate split-K partials. C/D layout: row(m)=quad*4+reg, col(n)=lane&15.
    #pragma unroll
    for (int mt = 0; mt < 4; ++mt) {
        const int mb = m0 + wm + mt * 16 + quad * 4;
        #pragma unroll
        for (int nt = 0; nt < 4; ++nt) {
            const int n = n0 + wn + nt * 16 + l16;
            #pragma unroll
            for (int r = 0; r < 4; ++r)
                unsafeAtomicAdd(&out[(mb + r) * O_DIM + n], acc[mt][nt][r]);
        }
    }
}

// ---- fallback (round-1 style) if workspace is too small for bf16 W ----
__global__ __launch_bounds__(256, 2) void gl_gemm_fb(const float* __restrict__ x1,
                                                     const float* __restrict__ x2,
                                                     const float* __restrict__ W,
                                                     float* __restrict__ out) {
    __shared__ unsigned short Ab[BM * STR];
    __shared__ unsigned short Bb2[BM * STR];

    const int tid  = threadIdx.x;
    const int lane = tid & 63;
    const int wid  = tid >> 6;
    const int wm   = (wid >> 1) * 64;
    const int wn   = (wid & 1) * 64;
    const int quad = lane >> 4;
    const int l16  = lane & 15;
    const int m0   = blockIdx.y * BM;
    const int n0   = blockIdx.x * BN;
    const int kk0  = blockIdx.z * (KDIM / BK / 4);

    const int srow = tid >> 4;
    const int scol = (tid & 15) * 4;

    f32x4 acc[4][4] = {};

    for (int kk = kk0; kk < kk0 + (KDIM / BK / 4); ++kk) {
        const int g = kk >> 6;
        const int i = kk & 63;
        __syncthreads();
        #pragma unroll
        for (int c = 0; c < 8; ++c) {
            const int r = srow + c * 16;
            const float x1v = x1[(m0 + r) * H_DIM + g * BSZ + i];
            const f32x4 v = *reinterpret_cast<const f32x4*>(
                &x2[(m0 + r) * H_DIM + g * BSZ + scol]);
            ushort4 h;
            h.x = f2b(v.x * x1v); h.y = f2b(v.y * x1v);
            h.z = f2b(v.z * x1v); h.w = f2b(v.w * x1v);
            *reinterpret_cast<ushort4*>(&Ab[r * STR + scol]) = h;
        }
        #pragma unroll
        for (int c = 0; c < 8; ++c) {
            const int r = srow + c * 16;
            const f32x4 v = *reinterpret_cast<const f32x4*>(
                &W[(size_t)(n0 + r) * KDIM + (size_t)kk * BK + scol]);
            ushort4 h;
            h.x = f2b(v.x); h.y = f2b(v.y); h.z = f2b(v.z); h.w = f2b(v.w);
            *reinterpret_cast<ushort4*>(&Bb2[r * STR + scol]) = h;
        }
        __syncthreads();
        #pragma unroll
        for (int ks = 0; ks < 2; ++ks) {
            const int koff = ks * 32 + quad * 8;
            bf16x8 af[4], bfr[4];
            #pragma unroll
            for (int mt = 0; mt < 4; ++mt)
                af[mt] = *reinterpret_cast<const bf16x8*>(
                    &Ab[(wm + mt * 16 + l16) * STR + koff]);
            #pragma unroll
            for (int nt = 0; nt < 4; ++nt)
                bfr[nt] = *reinterpret_cast<const bf16x8*>(
                    &Bb2[(wn + nt * 16 + l16) * STR + koff]);
            #pragma unroll
            for (int mt = 0; mt < 4; ++mt)
                #pragma unroll
                for (int nt = 0; nt < 4; ++nt)
                    acc[mt][nt] = __builtin_amdgcn_mfma_f32_16x16x32_bf16(
                        af[mt], bfr[nt], acc[mt][nt], 0, 0, 0);
        }
    }
    #pragma unroll
    for (int mt = 0; mt < 4; ++mt) {
        const int mb = m0 + wm + mt * 16 + quad * 4;
        #pragma unroll
        for (int nt = 0; nt < 4; ++nt) {
            const int n = n0 + wn + nt * 16 + l16;
            #pragma unroll
            for (int r = 0; r < 4; ++r)
                unsafeAtomicAdd(&out[(mb + r) * O_DIM + n], acc[mt][nt][r]);
        }
    }
}

extern "C" void kernel_launch(void* const* d_in, const int* in_sizes, int n_in,
                              void* d_out, int out_size, void* d_ws, size_t ws_size,
                              hipStream_t stream) {
    const float* x1 = (const float*)d_in[0];
    const float* x2 = (const float*)d_in[1];
    const float* W  = (const float*)d_in[2];
    const float* b  = (const float*)d_in[3];
    float* out = (float*)d_out;

    const size_t w_bf16_bytes = (size_t)O_DIM * KDIM * sizeof(unsigned short); // 134 MB

    // init out with bias (d_out is poisoned before every timed launch)
    gl_init<<<dim3((L_DIM * O_DIM / 4) / 256), dim3(256), 0, stream>>>(b, out);

    if (ws_size >= w_bf16_bytes) {
        unsigned short* Wb = (unsigned short*)d_ws;
        w_convert<<<dim3((size_t)O_DIM * KDIM / 16 / 256), dim3(256), 0, stream>>>(W, Wb);
        // 1D grid: 8(n) x 16(m) x 8(k) = 1024 blocks = exact 4/CU residency
        gl_gemm<<<dim3(NTILE * MTILE * SPLITK), dim3(256), 0, stream>>>(x1, x2, Wb, out);
    } else {
        dim3 grid(O_DIM / BN, L_DIM / BM, 4);
        gl_gemm_fb<<<grid, dim3(256), 0, stream>>>(x1, x2, W, out);
    }
}

// Round 6
// 1258.393 us; speedup vs baseline: 1.8977x; 1.8977x over previous
//
#include <hip/hip_runtime.h>
#include <hip/hip_bf16.h>
#include <stdint.h>

// GroupLinear: out[l,o] = sum_{g,i,j} x1[l,g*64+i]*x2[l,g*64+j]*W[o,(g*64+i)*64+j] + b[o]
// Round 5b: LDS-free, barrier-free GEMM (r5 with the bit_cast compile fix).
// Facts from r1-r4:
//  - global_load_lds W-traffic is NOT L2-retained (r2/r3: 17x refetch, 2.4 GB)
//  - regular loads ARE retained (r1: FETCH 200 MB < |W|)
//  - register double-buffer at occupancy-4 spills (r4: 3.6 GB scratch writes)
// Every MFMA fragment is built/loaded directly in registers:
//  - A-frag: x2 k-slice cached in 64 VGPRs per g (reload /64 iters); per iter only
//    4 x1 scalars + v_cvt_pk_bf16_f32 packing.
//  - B-frag: direct 16B loads of bf16 W (full-line coalesced, L2-shared by 16 m-blocks).
// No __syncthreads in the K-loop. 512 blocks = exact 2/CU at bounds(256,2).

#define L_DIM 2048
#define H_DIM 1024
#define O_DIM 1024
#define KDIM  65536

constexpr int BM = 128, BN = 128;
constexpr int SPLITK = 4;   // 4 g-groups of 4 each per block

typedef __attribute__((ext_vector_type(8))) short bf16x8;
typedef __attribute__((ext_vector_type(4))) float f32x4;
typedef __attribute__((ext_vector_type(4))) unsigned int u32x4;

__device__ __forceinline__ unsigned short f2b(float x) {
    __hip_bfloat16 h = __float2bfloat16(x);
    unsigned short u;
    __builtin_memcpy(&u, &h, 2);
    return u;
}

__device__ __forceinline__ unsigned pk2(float a, float b) {
    float2 t; t.x = a; t.y = b;
    __hip_bfloat162 h = __float22bfloat162_rn(t);   // v_cvt_pk_bf16_f32
    unsigned u;
    __builtin_memcpy(&u, &h, 4);
    return u;
}

// ---- W fp32 -> bf16, coalesced grid-strided passes ----
__global__ __launch_bounds__(256) void w_convert(const float* __restrict__ W,
                                                 unsigned short* __restrict__ Wb) {
    const size_t idx = (size_t)blockIdx.x * 256 + threadIdx.x;    // f32x4 chunk id
    const size_t stride = (size_t)gridDim.x * 256;
    const f32x4* src = reinterpret_cast<const f32x4*>(W);
    ushort4* dst = reinterpret_cast<ushort4*>(Wb);
    #pragma unroll
    for (int p = 0; p < 4; ++p) {
        f32x4 v = src[idx + (size_t)p * stride];
        ushort4 h;
        h.x = f2b(v.x); h.y = f2b(v.y); h.z = f2b(v.z); h.w = f2b(v.w);
        dst[idx + (size_t)p * stride] = h;
    }
}

// ---- out[l][o] = bias[o] (atomic-accumulation base) ----
__global__ __launch_bounds__(256) void gl_init(const float* __restrict__ bias,
                                               float* __restrict__ out) {
    int idx = blockIdx.x * 256 + threadIdx.x;          // float4 index
    int o = (idx * 4) & (O_DIM - 1);
    f32x4 bv = *reinterpret_cast<const f32x4*>(bias + o);
    reinterpret_cast<f32x4*>(out)[idx] = bv;
}

// ---- main GEMM: fragment-direct, no LDS, no barriers ----
__global__ __launch_bounds__(256, 2) void gl_gemm(const float* __restrict__ x1,
                                                  const float* __restrict__ x2,
                                                  const unsigned short* __restrict__ Wb,
                                                  float* __restrict__ out) {
    const int tid  = threadIdx.x;
    const int lane = tid & 63;
    const int wid  = tid >> 6;
    const int wm   = (wid >> 1) * 64;   // wave row offset in tile
    const int wn   = (wid & 1) * 64;    // wave col offset in tile
    const int quad = lane >> 4;
    const int l16  = lane & 15;

    // n in low 3 bits: all m-blocks + k-groups of one n-slab co-locate per XCD (L2 W reuse)
    const int id = blockIdx.x;
    const int n0 = (id & 7) * BN;
    const int m0 = ((id >> 3) & 15) * BM;
    const int g0 = (id >> 7) * 4;       // 4 g's per split-K block

    unsigned aoff[4], boff[4];          // 32-bit element offsets (keep addr regs cheap)
    #pragma unroll
    for (int t = 0; t < 4; ++t) {
        aoff[t] = (unsigned)(m0 + wm + t * 16 + l16) * H_DIM;   // x1/x2 row (floats)
        boff[t] = (unsigned)(n0 + wn + t * 16 + l16) * KDIM;    // Wb row (shorts, <4G)
    }
    const unsigned qo = quad * 8;

    f32x4 acc[4][4] = {};

    f32x4 x2c[4][4];        // per-g x2 k-slice cache: [mt][ks*2+half]
    bf16x8 bA[2][4], bB[2][4];
    float  xA[4], xB[4];

    for (int gi = 0; gi < 4; ++gi) {
        const int g = g0 + gi;
        const unsigned gb = (unsigned)g * 64;       // k-index base within x rows
        const unsigned wb = gb * 64;                // element base within W rows

        // refill x2 cache for this g (once per 64 iters)
        #pragma unroll
        for (int mt = 0; mt < 4; ++mt) {
            const float* p = x2 + aoff[mt] + gb + qo;
            x2c[mt][0] = *reinterpret_cast<const f32x4*>(p);
            x2c[mt][1] = *reinterpret_cast<const f32x4*>(p + 4);
            x2c[mt][2] = *reinterpret_cast<const f32x4*>(p + 32);
            x2c[mt][3] = *reinterpret_cast<const f32x4*>(p + 36);
        }

        auto loadB = [&](int i, bf16x8 (&bf)[2][4]) {
            const unsigned kb = wb + (unsigned)i * 64 + qo;
            #pragma unroll
            for (int ks = 0; ks < 2; ++ks)
                #pragma unroll
                for (int nt = 0; nt < 4; ++nt)
                    bf[ks][nt] = *reinterpret_cast<const bf16x8*>(
                        Wb + boff[nt] + kb + ks * 32);
        };
        auto loadX1 = [&](int i, float (&v)[4]) {
            #pragma unroll
            for (int mt = 0; mt < 4; ++mt)
                v[mt] = x1[aoff[mt] + gb + i];
        };
        auto compute = [&](const float (&v)[4], const bf16x8 (&bf)[2][4]) {
            #pragma unroll
            for (int ks = 0; ks < 2; ++ks) {
                bf16x8 af[4];
                #pragma unroll
                for (int mt = 0; mt < 4; ++mt) {
                    f32x4 lo = x2c[mt][ks * 2]     * v[mt];
                    f32x4 hi = x2c[mt][ks * 2 + 1] * v[mt];
                    u32x4 pk;
                    pk[0] = pk2(lo.x, lo.y); pk[1] = pk2(lo.z, lo.w);
                    pk[2] = pk2(hi.x, hi.y); pk[3] = pk2(hi.z, hi.w);
                    af[mt] = __builtin_bit_cast(bf16x8, pk);
                }
                #pragma unroll
                for (int mt = 0; mt < 4; ++mt)
                    #pragma unroll
                    for (int nt = 0; nt < 4; ++nt)
                        acc[mt][nt] = __builtin_amdgcn_mfma_f32_16x16x32_bf16(
                            af[mt], bf[ks][nt], acc[mt][nt], 0, 0, 0);
            }
        };

        loadB(0, bA);
        loadX1(0, xA);
        for (int i = 0; i < 64; i += 2) {
            loadB(i + 1, bB);           // in flight through compute(i)
            loadX1(i + 1, xB);
            compute(xA, bA);
            if (i + 2 < 64) {
                loadB(i + 2, bA);       // in flight through compute(i+1)
                loadX1(i + 2, xA);
            }
            compute(xB, bB);
        }
    }

    // Epilogue: accumulate split-K partials. C/D layout: row(m)=quad*4+reg, col(n)=lane&15.
    #pragma unroll
    for (int mt = 0; mt < 4; ++mt) {
        const int mb = m0 + wm + mt * 16 + quad * 4;
        #pragma unroll
        for (int nt = 0; nt < 4; ++nt) {
            const int n = n0 + wn + nt * 16 + l16;
            #pragma unroll
            for (int r = 0; r < 4; ++r)
                unsafeAtomicAdd(&out[(mb + r) * O_DIM + n], acc[mt][nt][r]);
        }
    }
}

// ---- fallback (round-1 style, fp32 W) if workspace too small for bf16 W ----
constexpr int STR = 72;
__global__ __launch_bounds__(256, 2) void gl_gemm_fb(const float* __restrict__ x1,
                                                     const float* __restrict__ x2,
                                                     const float* __restrict__ W,
                                                     float* __restrict__ out) {
    __shared__ unsigned short Ab[BM * STR];
    __shared__ unsigned short Bb2[BM * STR];

    const int tid  = threadIdx.x;
    const int lane = tid & 63;
    const int wid  = tid >> 6;
    const int wm   = (wid >> 1) * 64;
    const int wn   = (wid & 1) * 64;
    const int quad = lane >> 4;
    const int l16  = lane & 15;
    const int m0   = blockIdx.y * BM;
    const int n0   = blockIdx.x * BN;
    const int kk0  = blockIdx.z * (KDIM / 64 / 4);

    const int srow = tid >> 4;
    const int scol = (tid & 15) * 4;

    f32x4 acc[4][4] = {};

    for (int kk = kk0; kk < kk0 + (KDIM / 64 / 4); ++kk) {
        const int g = kk >> 6;
        const int i = kk & 63;
        __syncthreads();
        #pragma unroll
        for (int c = 0; c < 8; ++c) {
            const int r = srow + c * 16;
            const float x1v = x1[(m0 + r) * H_DIM + g * 64 + i];
            const f32x4 v = *reinterpret_cast<const f32x4*>(
                &x2[(m0 + r) * H_DIM + g * 64 + scol]);
            ushort4 h;
            h.x = f2b(v.x * x1v); h.y = f2b(v.y * x1v);
            h.z = f2b(v.z * x1v); h.w = f2b(v.w * x1v);
            *reinterpret_cast<ushort4*>(&Ab[r * STR + scol]) = h;
        }
        #pragma unroll
        for (int c = 0; c < 8; ++c) {
            const int r = srow + c * 16;
            const f32x4 v = *reinterpret_cast<const f32x4*>(
                &W[(size_t)(n0 + r) * KDIM + (size_t)kk * 64 + scol]);
            ushort4 h;
            h.x = f2b(v.x); h.y = f2b(v.y); h.z = f2b(v.z); h.w = f2b(v.w);
            *reinterpret_cast<ushort4*>(&Bb2[r * STR + scol]) = h;
        }
        __syncthreads();
        #pragma unroll
        for (int ks = 0; ks < 2; ++ks) {
            const int koff = ks * 32 + quad * 8;
            bf16x8 af[4], bfr[4];
            #pragma unroll
            for (int mt = 0; mt < 4; ++mt)
                af[mt] = *reinterpret_cast<const bf16x8*>(
                    &Ab[(wm + mt * 16 + l16) * STR + koff]);
            #pragma unroll
            for (int nt = 0; nt < 4; ++nt)
                bfr[nt] = *reinterpret_cast<const bf16x8*>(
                    &Bb2[(wn + nt * 16 + l16) * STR + koff]);
            #pragma unroll
            for (int mt = 0; mt < 4; ++mt)
                #pragma unroll
                for (int nt = 0; nt < 4; ++nt)
                    acc[mt][nt] = __builtin_amdgcn_mfma_f32_16x16x32_bf16(
                        af[mt], bfr[nt], acc[mt][nt], 0, 0, 0);
        }
    }
    #pragma unroll
    for (int mt = 0; mt < 4; ++mt) {
        const int mb = m0 + wm + mt * 16 + quad * 4;
        #pragma unroll
        for (int nt = 0; nt < 4; ++nt) {
            const int n = n0 + wn + nt * 16 + l16;
            #pragma unroll
            for (int r = 0; r < 4; ++r)
                unsafeAtomicAdd(&out[(mb + r) * O_DIM + n], acc[mt][nt][r]);
        }
    }
}

extern "C" void kernel_launch(void* const* d_in, const int* in_sizes, int n_in,
                              void* d_out, int out_size, void* d_ws, size_t ws_size,
                              hipStream_t stream) {
    const float* x1 = (const float*)d_in[0];
    const float* x2 = (const float*)d_in[1];
    const float* W  = (const float*)d_in[2];
    const float* b  = (const float*)d_in[3];
    float* out = (float*)d_out;

    const size_t w_bf16_bytes = (size_t)O_DIM * KDIM * sizeof(unsigned short); // 134 MB

    // init out with bias (d_out is poisoned before every timed launch)
    gl_init<<<dim3((L_DIM * O_DIM / 4) / 256), dim3(256), 0, stream>>>(b, out);

    if (ws_size >= w_bf16_bytes) {
        unsigned short* Wb = (unsigned short*)d_ws;
        w_convert<<<dim3((size_t)O_DIM * KDIM / 16 / 256), dim3(256), 0, stream>>>(W, Wb);
        // 1D grid: 8(n) x 16(m) x 4(k) = 512 blocks = exact 2/CU at bounds(256,2)
        gl_gemm<<<dim3(8 * 16 * SPLITK), dim3(256), 0, stream>>>(x1, x2, Wb, out);
    } else {
        dim3 grid(O_DIM / BN, L_DIM / BM, 4);
        gl_gemm_fb<<<grid, dim3(256), 0, stream>>>(x1, x2, W, out);
    }
}

// Round 7
// 813.399 us; speedup vs baseline: 2.9359x; 1.5471x over previous
//
#include <hip/hip_runtime.h>
#include <hip/hip_bf16.h>
#include <stdint.h>

// GroupLinear: out[l,o] = sum_{g,i,j} x1[l,g*64+i]*x2[l,g*64+j]*W[o,(g*64+i)*64+j] + b[o]
// Round 7: hybrid. A-frags register-built (r6 path: x2c per-g cache + x1 prefetch);
// B-tile LDS double-buffered, staged with REGULAR loads (L2-retained, r1/r6 evidence)
// as a 16-reg transient in flight across the MFMA phase. One barrier per iter.
// Facts: global_load_lds not L2-retained (r2/r3); reg-dbuf spills/serializes when the
// live set exceeds the arch budget (r4: scratch 3.6GB; r6: compiler serialization at 128).

#define L_DIM 2048
#define H_DIM 1024
#define O_DIM 1024
#define KDIM  65536

constexpr int BM = 128, BN = 128;
constexpr int SPLITK = 4;
constexpr int KITERS = 1024 / SPLITK;   // 256 (g,i) pairs per block, K-advance 64 each
constexpr int BSTR = 72;                // B LDS row stride in shorts (64+8 pad)

typedef __attribute__((ext_vector_type(8))) short bf16x8;
typedef __attribute__((ext_vector_type(8))) unsigned short u16x8;
typedef __attribute__((ext_vector_type(4))) float f32x4;
typedef __attribute__((ext_vector_type(4))) unsigned int u32x4;

__device__ __forceinline__ unsigned short f2b(float x) {
    __hip_bfloat16 h = __float2bfloat16(x);
    unsigned short u;
    __builtin_memcpy(&u, &h, 2);
    return u;
}

__device__ __forceinline__ unsigned pk2(float a, float b) {
    float2 t; t.x = a; t.y = b;
    __hip_bfloat162 h = __float22bfloat162_rn(t);   // v_cvt_pk_bf16_f32
    unsigned u;
    __builtin_memcpy(&u, &h, 4);
    return u;
}

// ---- W fp32 -> bf16, coalesced grid-strided passes ----
__global__ __launch_bounds__(256) void w_convert(const float* __restrict__ W,
                                                 unsigned short* __restrict__ Wb) {
    const size_t idx = (size_t)blockIdx.x * 256 + threadIdx.x;
    const size_t stride = (size_t)gridDim.x * 256;
    const f32x4* src = reinterpret_cast<const f32x4*>(W);
    ushort4* dst = reinterpret_cast<ushort4*>(Wb);
    #pragma unroll
    for (int p = 0; p < 4; ++p) {
        f32x4 v = src[idx + (size_t)p * stride];
        ushort4 h;
        h.x = f2b(v.x); h.y = f2b(v.y); h.z = f2b(v.z); h.w = f2b(v.w);
        dst[idx + (size_t)p * stride] = h;
    }
}

// ---- out[l][o] = bias[o] (atomic-accumulation base) ----
__global__ __launch_bounds__(256) void gl_init(const float* __restrict__ bias,
                                               float* __restrict__ out) {
    int idx = blockIdx.x * 256 + threadIdx.x;
    int o = (idx * 4) & (O_DIM - 1);
    f32x4 bv = *reinterpret_cast<const f32x4*>(bias + o);
    reinterpret_cast<f32x4*>(out)[idx] = bv;
}

// ---- main GEMM ----
__global__ __launch_bounds__(256, 2) void gl_gemm(const float* __restrict__ x1,
                                                  const float* __restrict__ x2,
                                                  const unsigned short* __restrict__ Wb,
                                                  float* __restrict__ out) {
    __shared__ unsigned short Bb[2][BN * BSTR];   // 2 x 18 KB

    const int tid  = threadIdx.x;
    const int lane = tid & 63;
    const int wid  = tid >> 6;
    const int wm   = (wid >> 1) * 64;
    const int wn   = (wid & 1) * 64;
    const int quad = lane >> 4;
    const int l16  = lane & 15;

    // n in low 3 bits -> all blocks sharing one W n-slab co-locate per XCD (L2 reuse; r6: FETCH 175MB)
    const int id  = blockIdx.x;
    const int n0  = (id & 7) * BN;
    const int m0  = ((id >> 3) & 15) * BM;
    const int kk0 = (id >> 7) * KITERS;     // (g,i)-pair index base, multiple of 64

    unsigned aoff[4];                       // x1/x2 row offsets (floats)
    #pragma unroll
    for (int t = 0; t < 4; ++t)
        aoff[t] = (unsigned)(m0 + wm + t * 16 + l16) * H_DIM;
    const unsigned qo = quad * 8;

    // B staging: thread covers rows (tid>>3)+32p, 16B chunk (tid&7)*8 shorts
    const int brow = tid >> 3;
    const int bcol = (tid & 7) * 8;
    const unsigned short* gB = Wb + (size_t)(n0 + brow) * KDIM + (size_t)kk0 * 64 + bcol;
    const int bl = brow * BSTR + bcol;

    f32x4 acc[4][4] = {};
    f32x4 x2c[4][4];        // per-g x2 slice cache: [mt][ks*2+half]
    u16x8 rB[4];            // transient staging regs (in flight across MFMA phase)
    float xc[4], xn[4];     // x1 current / next

    auto loadB = [&](int it) {
        const unsigned short* gp = gB + (size_t)it * 64;
        #pragma unroll
        for (int p = 0; p < 4; ++p)
            rB[p] = *reinterpret_cast<const u16x8*>(gp + (size_t)p * 32 * KDIM);
    };
    auto writeB = [&](int buf) {
        #pragma unroll
        for (int p = 0; p < 4; ++p)
            *reinterpret_cast<u16x8*>(&Bb[buf][bl + p * 32 * BSTR]) = rB[p];
    };
    auto loadX1 = [&](int it, float (&v)[4]) {
        const unsigned kc = (unsigned)(kk0 + it);   // x1 col = g*64+i
        #pragma unroll
        for (int mt = 0; mt < 4; ++mt)
            v[mt] = x1[aoff[mt] + kc];
    };

    // prologue: stage tile 0
    loadB(0);
    writeB(0);
    loadX1(0, xc);
    __syncthreads();

    for (int it = 0; it < KITERS; ++it) {
        const int cur = it & 1;

        if ((it & 63) == 0) {               // refill x2c for this g (wave-uniform branch)
            const unsigned gb = (unsigned)(kk0 + it);   // col base = g*64
            #pragma unroll
            for (int mt = 0; mt < 4; ++mt) {
                const float* p = x2 + aoff[mt] + gb + qo;
                x2c[mt][0] = *reinterpret_cast<const f32x4*>(p);
                x2c[mt][1] = *reinterpret_cast<const f32x4*>(p + 4);
                x2c[mt][2] = *reinterpret_cast<const f32x4*>(p + 32);
                x2c[mt][3] = *reinterpret_cast<const f32x4*>(p + 36);
            }
        }

        const bool hn = (it + 1 < KITERS);
        if (hn) {                           // prefetch next tile (covered by MFMA phase)
            loadB(it + 1);
            loadX1(it + 1, xn);
        }

        // compute from Bb[cur] with register-built A-frags
        #pragma unroll
        for (int ks = 0; ks < 2; ++ks) {
            const int koff = ks * 32 + qo;
            bf16x8 af[4], bfr[4];
            #pragma unroll
            for (int nt = 0; nt < 4; ++nt)
                bfr[nt] = *reinterpret_cast<const bf16x8*>(
                    &Bb[cur][(wn + nt * 16 + l16) * BSTR + koff]);
            #pragma unroll
            for (int mt = 0; mt < 4; ++mt) {
                f32x4 lo = x2c[mt][ks * 2]     * xc[mt];
                f32x4 hi = x2c[mt][ks * 2 + 1] * xc[mt];
                u32x4 pk;
                pk[0] = pk2(lo.x, lo.y); pk[1] = pk2(lo.z, lo.w);
                pk[2] = pk2(hi.x, hi.y); pk[3] = pk2(hi.z, hi.w);
                af[mt] = __builtin_bit_cast(bf16x8, pk);
            }
            #pragma unroll
            for (int mt = 0; mt < 4; ++mt)
                #pragma unroll
                for (int nt = 0; nt < 4; ++nt)
                    acc[mt][nt] = __builtin_amdgcn_mfma_f32_16x16x32_bf16(
                        af[mt], bfr[nt], acc[mt][nt], 0, 0, 0);
        }

        if (hn) writeB(cur ^ 1);            // stage next tile into the other buffer
        #pragma unroll
        for (int mt = 0; mt < 4; ++mt) xc[mt] = xn[mt];
        __syncthreads();                    // single barrier per iter
    }

    // Epilogue: split-K partials. C/D: row(m)=quad*4+reg, col(n)=lane&15.
    #pragma unroll
    for (int mt = 0; mt < 4; ++mt) {
        const int mb = m0 + wm + mt * 16 + quad * 4;
        #pragma unroll
        for (int nt = 0; nt < 4; ++nt) {
            const int n = n0 + wn + nt * 16 + l16;
            #pragma unroll
            for (int r = 0; r < 4; ++r)
                unsafeAtomicAdd(&out[(mb + r) * O_DIM + n], acc[mt][nt][r]);
        }
    }
}

// ---- fallback (fp32 W, LDS staging) if workspace too small for bf16 W ----
constexpr int STR = 72;
__global__ __launch_bounds__(256, 2) void gl_gemm_fb(const float* __restrict__ x1,
                                                     const float* __restrict__ x2,
                                                     const float* __restrict__ W,
                                                     float* __restrict__ out) {
    __shared__ unsigned short Ab[BM * STR];
    __shared__ unsigned short Bb2[BM * STR];

    const int tid  = threadIdx.x;
    const int lane = tid & 63;
    const int wid  = tid >> 6;
    const int wm   = (wid >> 1) * 64;
    const int wn   = (wid & 1) * 64;
    const int quad = lane >> 4;
    const int l16  = lane & 15;
    const int m0   = blockIdx.y * BM;
    const int n0   = blockIdx.x * BN;
    const int kk0  = blockIdx.z * (1024 / 4);

    const int srow = tid >> 4;
    const int scol = (tid & 15) * 4;

    f32x4 acc[4][4] = {};

    for (int kk = kk0; kk < kk0 + (1024 / 4); ++kk) {
        const int g = kk >> 6;
        const int i = kk & 63;
        __syncthreads();
        #pragma unroll
        for (int c = 0; c < 8; ++c) {
            const int r = srow + c * 16;
            const float x1v = x1[(m0 + r) * H_DIM + g * 64 + i];
            const f32x4 v = *reinterpret_cast<const f32x4*>(
                &x2[(m0 + r) * H_DIM + g * 64 + scol]);
            ushort4 h;
            h.x = f2b(v.x * x1v); h.y = f2b(v.y * x1v);
            h.z = f2b(v.z * x1v); h.w = f2b(v.w * x1v);
            *reinterpret_cast<ushort4*>(&Ab[r * STR + scol]) = h;
        }
        #pragma unroll
        for (int c = 0; c < 8; ++c) {
            const int r = srow + c * 16;
            const f32x4 v = *reinterpret_cast<const f32x4*>(
                &W[(size_t)(n0 + r) * KDIM + (size_t)kk * 64 + scol]);
            ushort4 h;
            h.x = f2b(v.x); h.y = f2b(v.y); h.z = f2b(v.z); h.w = f2b(v.w);
            *reinterpret_cast<ushort4*>(&Bb2[r * STR + scol]) = h;
        }
        __syncthreads();
        #pragma unroll
        for (int ks = 0; ks < 2; ++ks) {
            const int koff = ks * 32 + quad * 8;
            bf16x8 af[4], bfr[4];
            #pragma unroll
            for (int mt = 0; mt < 4; ++mt)
                af[mt] = *reinterpret_cast<const bf16x8*>(
                    &Ab[(wm + mt * 16 + l16) * STR + koff]);
            #pragma unroll
            for (int nt = 0; nt < 4; ++nt)
                bfr[nt] = *reinterpret_cast<const bf16x8*>(
                    &Bb2[(wn + nt * 16 + l16) * STR + koff]);
            #pragma unroll
            for (int mt = 0; mt < 4; ++mt)
                #pragma unroll
                for (int nt = 0; nt < 4; ++nt)
                    acc[mt][nt] = __builtin_amdgcn_mfma_f32_16x16x32_bf16(
                        af[mt], bfr[nt], acc[mt][nt], 0, 0, 0);
        }
    }
    #pragma unroll
    for (int mt = 0; mt < 4; ++mt) {
        const int mb = m0 + wm + mt * 16 + quad * 4;
        #pragma unroll
        for (int nt = 0; nt < 4; ++nt) {
            const int n = n0 + wn + nt * 16 + l16;
            #pragma unroll
            for (int r = 0; r < 4; ++r)
                unsafeAtomicAdd(&out[(mb + r) * O_DIM + n], acc[mt][nt][r]);
        }
    }
}

extern "C" void kernel_launch(void* const* d_in, const int* in_sizes, int n_in,
                              void* d_out, int out_size, void* d_ws, size_t ws_size,
                              hipStream_t stream) {
    const float* x1 = (const float*)d_in[0];
    const float* x2 = (const float*)d_in[1];
    const float* W  = (const float*)d_in[2];
    const float* b  = (const float*)d_in[3];
    float* out = (float*)d_out;

    const size_t w_bf16_bytes = (size_t)O_DIM * KDIM * sizeof(unsigned short); // 134 MB

    gl_init<<<dim3((L_DIM * O_DIM / 4) / 256), dim3(256), 0, stream>>>(b, out);

    if (ws_size >= w_bf16_bytes) {
        unsigned short* Wb = (unsigned short*)d_ws;
        w_convert<<<dim3((size_t)O_DIM * KDIM / 16 / 256), dim3(256), 0, stream>>>(W, Wb);
        // 1D grid: 8(n) x 16(m) x 4(k) = 512 blocks = exact 2/CU at bounds(256,2)
        gl_gemm<<<dim3(8 * 16 * SPLITK), dim3(256), 0, stream>>>(x1, x2, Wb, out);
    } else {
        dim3 grid(O_DIM / BN, L_DIM / BM, 4);
        gl_gemm_fb<<<grid, dim3(256), 0, stream>>>(x1, x2, W, out);
    }
}